// Round 3
// baseline (228.159 us; speedup 1.0000x reference)
//
#include <hip/hip_runtime.h>

constexpr int EMB  = 128;   // EMB_DIM
constexpr int H1D  = 256;   // 2*HIDDEN
constexpr int H2D  = 128;   // HIDDEN
constexpr int VOC  = 4096;  // VOCAB

// ---------------------------------------------------------------- init
__global__ void k_init(int* cnt, int* count, float* wsum, int* nflag, int n) {
    int i = blockIdx.x * blockDim.x + threadIdx.x;
    if (i < n) { cnt[i] = 0; count[i] = 0; }
    if (i < H1D) wsum[i] = 0.0f;
    if (i == 0) *nflag = 0;
}

// ------------------------------------------------- in-degree histogram
__global__ void k_hist(const int* __restrict__ col, int* cnt, int ne) {
    int e = blockIdx.x * blockDim.x + threadIdx.x;
    if (e < ne) atomicAdd(&cnt[col[e]], 1);
}

// --------------------------------------------- x_position multiplicities
__global__ void k_count(const int* __restrict__ xpos, int* count, int np) {
    int p = blockIdx.x * blockDim.x + threadIdx.x;
    if (p < np) atomicAdd(&count[xpos[p]], 1);
}

// ------------------------- dinv + wagg self-term init (non-atomic full write)
__global__ void k_dinv(const int* __restrict__ cnt, const int* __restrict__ count,
                       float* dinv, float* wagg, int n) {
    int i = blockIdx.x * blockDim.x + threadIdx.x;
    if (i < n) {
        float d = rsqrtf((float)cnt[i] + 1.0f);  // +1 self loop
        dinv[i] = d;
        int cv = count[i];
        wagg[i] = (cv > 0) ? (float)cv * d * d : 0.0f;
    }
}

// ---------------- wagg edge contributions: wagg[row] += count[col]*dinv[col]*dinv[row]
__global__ void k_waggE(const int* __restrict__ row, const int* __restrict__ col,
                        const int* __restrict__ count, const float* __restrict__ dinv,
                        float* wagg, int ne) {
    int e = blockIdx.x * blockDim.x + threadIdx.x;
    if (e < ne) {
        int c = col[e];
        int cc = count[c];
        if (cc > 0) {
            int r = row[e];
            atomicAdd(&wagg[r], (float)cc * dinv[c] * dinv[r]);
        }
    }
}

// ------------------------------------------------- 2-level exclusive scan
__global__ void k_scan_local(const int* __restrict__ cnt, int* offs, int* bsum, int n) {
    __shared__ int s[256];
    int t = threadIdx.x;
    int i = blockIdx.x * 256 + t;
    int v = (i < n) ? cnt[i] : 0;
    s[t] = v;
    __syncthreads();
    for (int off = 1; off < 256; off <<= 1) {
        int add = (t >= off) ? s[t - off] : 0;
        __syncthreads();
        s[t] += add;
        __syncthreads();
    }
    if (i < n) offs[i] = s[t] - v;
    if (t == 255) bsum[blockIdx.x] = s[255];
}

__global__ void k_scan_bsum(const int* __restrict__ bsum, int* boff, int nb) {
    __shared__ int s[256];
    int t = threadIdx.x;
    int v = (t < nb) ? bsum[t] : 0;
    s[t] = v;
    __syncthreads();
    for (int off = 1; off < 256; off <<= 1) {
        int add = (t >= off) ? s[t - off] : 0;
        __syncthreads();
        s[t] += add;
        __syncthreads();
    }
    boff[t] = s[t] - v;
}

__global__ void k_scan_add(int* offs, int* cursor, const int* __restrict__ boff, int n) {
    int t = threadIdx.x;
    int i = blockIdx.x * 256 + t;
    if (i < n) {
        int o = offs[i] + boff[blockIdx.x];
        offs[i] = o;
        cursor[i] = o;
    }
}

// -------------------------------- needed-node list: u with wagg[u] > 0 (~17k)
__global__ void k_needlist(const float* __restrict__ wagg, int* needlist, int* nflag, int n) {
    int v = blockIdx.x * blockDim.x + threadIdx.x;
    if (v < n && wagg[v] > 0.0f) {
        int id = atomicAdd(nflag, 1);
        needlist[id] = v;
    }
}

// ---------------- scatter (filtered): only edges whose col is needed (~1/3)
__global__ void k_scatter(const int* __restrict__ row, const int* __restrict__ col,
                          const float* __restrict__ wagg, int* cursor, int* srow, int ne) {
    int e = blockIdx.x * blockDim.x + threadIdx.x;
    if (e < ne) {
        int c = col[e];
        if (wagg[c] > 0.0f) {
            int pos = atomicAdd(&cursor[c], 1);
            srow[pos] = row[e];
        }
    }
}

// ---------------------------------------------------- embW1 = emb @ W1
// 16 vocab rows per block; W1 streamed once per block (33 MB total L2 traffic)
constexpr int RPB = 16;
__global__ void k_embW1(const float* __restrict__ emb, const float* __restrict__ W1,
                        float* __restrict__ embW1) {
    __shared__ float er[RPB][EMB];   // 8 KB
    int t = threadIdx.x;             // 256 threads = output col
    int r0 = blockIdx.x * RPB;
    // cooperative load of 16x128 = 2048 floats (8 per thread, coalesced)
    for (int i = t; i < RPB * EMB; i += 256) {
        er[i / EMB][i % EMB] = emb[(size_t)r0 * EMB + i];
    }
    __syncthreads();
    float acc[RPB];
#pragma unroll
    for (int rr = 0; rr < RPB; rr++) acc[rr] = 0.0f;
    for (int k = 0; k < EMB; k++) {
        float w = W1[k * H1D + t];
#pragma unroll
        for (int rr = 0; rr < RPB; rr++) acc[rr] += er[rr][k] * w;
    }
#pragma unroll
    for (int rr = 0; rr < RPB; rr++) {
        embW1[(size_t)(r0 + rr) * H1D + t] = acc[rr];
    }
}

// -------------------- fused conv1+conv2 over needed nodes:
//   wsum[256] += wagg[v] * relu( b1 + dv^2*embW1[x[v]] + sum_e dinv[r]*dv*embW1[x[r]] )
// one wave per node (grid-stride); lanes prefetch edge indices in parallel,
// __shfl-broadcast, 4 independent row loads per unroll step.
__global__ void k_fconv(const int* __restrict__ needlist, const int* __restrict__ nneed_p,
                        const float* __restrict__ wagg, const int* __restrict__ x,
                        const int* __restrict__ srow, const int* __restrict__ offs,
                        const int* __restrict__ cnt, const float* __restrict__ dinv,
                        const float* __restrict__ embW1, const float* __restrict__ b1,
                        float* __restrict__ wsum) {
    int lane = threadIdx.x & 63;
    int wib  = threadIdx.x >> 6;                       // wave in block (0..3)
    int wid  = blockIdx.x * (blockDim.x >> 6) + wib;
    int nw   = gridDim.x * (blockDim.x >> 6);
    int nn   = *nneed_p;
    const float4* __restrict__ ew = (const float4*)embW1;   // row r = ew + r*64
    float4 bfrag = ((const float4*)b1)[lane];
    float4 acc2 = {0.0f, 0.0f, 0.0f, 0.0f};

    for (int i = wid; i < nn; i += nw) {
        int v = needlist[i];
        float dv = dinv[v];
        float wa = wagg[v];
        float4 s = ew[(size_t)x[v] * 64 + lane];
        float w0 = dv * dv;
        float4 acc;
        acc.x = bfrag.x + w0 * s.x;
        acc.y = bfrag.y + w0 * s.y;
        acc.z = bfrag.z + w0 * s.z;
        acc.w = bfrag.w + w0 * s.w;
        int start = offs[v], m = cnt[v];
        for (int base = 0; base < m; base += 64) {
            int mm = min(64, m - base);
            // lane-parallel index prefetch (breaks the serial dependent chain)
            int xr = 0; float wr = 0.0f;
            if (lane < mm) {
                int r = srow[start + base + lane];
                xr = x[r];
                wr = dinv[r] * dv;
            }
            int e = 0;
            for (; e + 4 <= mm; e += 4) {
                int i0 = __shfl(xr, e),     i1 = __shfl(xr, e + 1);
                int i2 = __shfl(xr, e + 2), i3 = __shfl(xr, e + 3);
                float q0 = __shfl(wr, e),     q1 = __shfl(wr, e + 1);
                float q2 = __shfl(wr, e + 2), q3 = __shfl(wr, e + 3);
                float4 t0 = ew[(size_t)i0 * 64 + lane];
                float4 t1 = ew[(size_t)i1 * 64 + lane];
                float4 t2 = ew[(size_t)i2 * 64 + lane];
                float4 t3 = ew[(size_t)i3 * 64 + lane];
                acc.x += q0 * t0.x + q1 * t1.x + q2 * t2.x + q3 * t3.x;
                acc.y += q0 * t0.y + q1 * t1.y + q2 * t2.y + q3 * t3.y;
                acc.z += q0 * t0.z + q1 * t1.z + q2 * t2.z + q3 * t3.z;
                acc.w += q0 * t0.w + q1 * t1.w + q2 * t2.w + q3 * t3.w;
            }
            for (; e < mm; e++) {
                int i0 = __shfl(xr, e);
                float q0 = __shfl(wr, e);
                float4 t0 = ew[(size_t)i0 * 64 + lane];
                acc.x += q0 * t0.x;
                acc.y += q0 * t0.y;
                acc.z += q0 * t0.z;
                acc.w += q0 * t0.w;
            }
        }
        acc2.x += wa * fmaxf(acc.x, 0.0f);
        acc2.y += wa * fmaxf(acc.y, 0.0f);
        acc2.z += wa * fmaxf(acc.z, 0.0f);
        acc2.w += wa * fmaxf(acc.w, 0.0f);
    }

    // block reduction: 4 waves x 256 cols in LDS, then one atomic per col per block
    __shared__ float red[4][H1D];
    red[wib][4 * lane + 0] = acc2.x;
    red[wib][4 * lane + 1] = acc2.y;
    red[wib][4 * lane + 2] = acc2.z;
    red[wib][4 * lane + 3] = acc2.w;
    __syncthreads();
    int t = threadIdx.x;
    float ssum = red[0][t] + red[1][t] + red[2][t] + red[3][t];
    atomicAdd(&wsum[t], ssum);
}

// ------------------------------ zmean = (wsum @ W2)/NP + b2   (1 block, 128 thr)
__global__ void k_zmean(const float* __restrict__ wsum, const float* __restrict__ W2,
                        const float* __restrict__ b2, float* zmean, float inv_np) {
    int j = threadIdx.x;
    float acc = 0.0f;
#pragma unroll 8
    for (int k = 0; k < H1D; k++) acc += wsum[k] * W2[k * H2D + j];
    zmean[j] = b2[j] + acc * inv_np;
}

// ------------------------------ out = zmean @ Wc + bc   (16 blocks x 256)
__global__ void k_out(const float* __restrict__ zmean, const float* __restrict__ Wc,
                      const float* __restrict__ bc, float* __restrict__ out) {
    __shared__ float z[H2D];
    int t = threadIdx.x;
    if (t < H2D) z[t] = zmean[t];
    __syncthreads();
    int c = blockIdx.x * blockDim.x + t;
    float acc = bc[c];
#pragma unroll 8
    for (int j = 0; j < H2D; j++) acc += z[j] * Wc[(size_t)j * VOC + c];
    out[c] = acc;
}

extern "C" void kernel_launch(void* const* d_in, const int* in_sizes, int n_in,
                              void* d_out, int out_size, void* d_ws, size_t ws_size,
                              hipStream_t stream) {
    const int n  = in_sizes[0];
    const int ne = in_sizes[1] / 2;
    const int np = in_sizes[2];

    const int*   x    = (const int*)d_in[0];
    const int*   ei   = (const int*)d_in[1];
    const int*   xpos = (const int*)d_in[2];
    const float* emb  = (const float*)d_in[3];
    const float* W1   = (const float*)d_in[4];
    const float* b1   = (const float*)d_in[5];
    const float* W2   = (const float*)d_in[6];
    const float* b2   = (const float*)d_in[7];
    const float* Wc   = (const float*)d_in[8];
    const float* bc   = (const float*)d_in[9];
    float*       out  = (float*)d_out;

    const int* row = ei;       // edge_index[0]
    const int* col = ei + ne;  // edge_index[1]

    char* p = (char*)d_ws;
    auto alloc = [&](size_t bytes) {
        char* r = p;
        p += (bytes + 255) & ~(size_t)255;
        return r;
    };
    int*   cnt      = (int*)alloc((size_t)n * 4);
    int*   offs     = (int*)alloc((size_t)n * 4);
    int*   cursor   = (int*)alloc((size_t)n * 4);
    int*   count    = (int*)alloc((size_t)n * 4);
    int*   needlist = (int*)alloc((size_t)n * 4);
    int*   srow     = (int*)alloc((size_t)ne * 4);
    int*   bsum     = (int*)alloc(256 * 4);
    int*   boff     = (int*)alloc(256 * 4);
    int*   nflag    = (int*)alloc(256 * 4);
    float* dinv     = (float*)alloc((size_t)n * 4);
    float* wagg     = (float*)alloc((size_t)n * 4);
    float* embW1    = (float*)alloc((size_t)VOC * H1D * 4);
    float* wsum     = (float*)alloc(H1D * 4);
    float* zmean    = (float*)alloc(H2D * 4);

    const int nb  = (n + 255) / 256;
    const int neb = (ne + 255) / 256;

    k_init<<<nb, 256, 0, stream>>>(cnt, count, wsum, nflag, n);
    k_hist<<<neb, 256, 0, stream>>>(col, cnt, ne);
    k_count<<<(np + 255) / 256, 256, 0, stream>>>(xpos, count, np);
    k_dinv<<<nb, 256, 0, stream>>>(cnt, count, dinv, wagg, n);
    k_waggE<<<neb, 256, 0, stream>>>(row, col, count, dinv, wagg, ne);
    k_scan_local<<<nb, 256, 0, stream>>>(cnt, offs, bsum, n);
    k_scan_bsum<<<1, 256, 0, stream>>>(bsum, boff, nb);
    k_scan_add<<<nb, 256, 0, stream>>>(offs, cursor, boff, n);
    k_needlist<<<nb, 256, 0, stream>>>(wagg, needlist, nflag, n);
    k_scatter<<<neb, 256, 0, stream>>>(row, col, wagg, cursor, srow, ne);
    k_embW1<<<VOC / RPB, 256, 0, stream>>>(emb, W1, embW1);
    k_fconv<<<512, 256, 0, stream>>>(needlist, nflag, wagg, x, srow, offs, cnt,
                                     dinv, embW1, b1, wsum);
    k_zmean<<<1, H2D, 0, stream>>>(wsum, W2, b2, zmean, 1.0f / (float)np);
    k_out<<<VOC / 256, 256, 0, stream>>>(zmean, Wc, bc, out);
}

// Round 4
// 217.663 us; speedup vs baseline: 1.0482x; 1.0482x over previous
//
#include <hip/hip_runtime.h>

constexpr int EMB  = 128;   // EMB_DIM
constexpr int H1D  = 256;   // 2*HIDDEN
constexpr int H2D  = 128;   // HIDDEN
constexpr int VOC  = 4096;  // VOCAB

// ---------------------------------------------------------------- init
__global__ void k_init(int* cnt, int* count, float* wsum, int* nflag, int* total, int n) {
    int i = blockIdx.x * blockDim.x + threadIdx.x;
    if (i < n) { cnt[i] = 0; count[i] = 0; }
    if (i < H1D) wsum[i] = 0.0f;
    if (i == 0) { *nflag = 0; *total = 0; }
}

// --------------------- fused: in-degree histogram + x_position multiplicity
__global__ void k_histcnt(const int* __restrict__ col, const int* __restrict__ xpos,
                          int* cnt, int* count, int ne, int np) {
    int e = blockIdx.x * blockDim.x + threadIdx.x;
    if (e < ne) atomicAdd(&cnt[col[e]], 1);
    if (e < np) atomicAdd(&count[xpos[e]], 1);
}

// ------------------------- dinv + wagg self-term init (non-atomic full write)
__global__ void k_dinv(const int* __restrict__ cnt, const int* __restrict__ count,
                       float* dinv, float* wagg, int n) {
    int i = blockIdx.x * blockDim.x + threadIdx.x;
    if (i < n) {
        float d = rsqrtf((float)cnt[i] + 1.0f);  // +1 self loop
        dinv[i] = d;
        int cv = count[i];
        wagg[i] = (cv > 0) ? (float)cv * d * d : 0.0f;
    }
}

// ---------------- wagg edge contributions: wagg[row] += count[col]*dinv[col]*dinv[row]
__global__ void k_waggE(const int* __restrict__ row, const int* __restrict__ col,
                        const int* __restrict__ count, const float* __restrict__ dinv,
                        float* wagg, int ne) {
    int e = blockIdx.x * blockDim.x + threadIdx.x;
    if (e < ne) {
        int c = col[e];
        int cc = count[c];
        if (cc > 0) {
            int r = row[e];
            atomicAdd(&wagg[r], (float)cc * dinv[c] * dinv[r]);
        }
    }
}

// ------- alloc: needlist append + CSR segment bump-allocation (scan-free).
// Wave-aggregated atomics: 2 atomics per wave instead of 2 per needed node.
__global__ void k_alloc(const float* __restrict__ wagg, const int* __restrict__ cnt,
                        int* needlist, int* nflag, int* total,
                        int* offs, int* cursor, int n) {
    int v = blockIdx.x * blockDim.x + threadIdx.x;
    int lane = threadIdx.x & 63;
    bool need = (v < n) && (wagg[v] > 0.0f);
    int cv = need ? cnt[v] : 0;
    // wave-inclusive scan of cv
    int incl = cv;
#pragma unroll
    for (int d = 1; d < 64; d <<= 1) {
        int t = __shfl_up(incl, d);
        if (lane >= d) incl += t;
    }
    int excl = incl - cv;
    int wave_total = __shfl(incl, 63);
    unsigned long long mask = __ballot(need);
    int rank = __popcll(mask & ((1ull << lane) - 1));
    int wcnt = __popcll(mask);
    int base_id = 0, base_off = 0;
    if (lane == 0) {
        if (wcnt > 0) base_id = atomicAdd(nflag, wcnt);
        if (wave_total > 0) base_off = atomicAdd(total, wave_total);
    }
    base_id  = __shfl(base_id, 0);
    base_off = __shfl(base_off, 0);
    if (need) {
        needlist[base_id + rank] = v;
        int o = base_off + excl;
        offs[v] = o;
        cursor[v] = o;
    }
}

// ---------------- scatter (filtered): only edges whose col is needed (~1/3)
__global__ void k_scatter(const int* __restrict__ row, const int* __restrict__ col,
                          const float* __restrict__ wagg, int* cursor, int* srow, int ne) {
    int e = blockIdx.x * blockDim.x + threadIdx.x;
    if (e < ne) {
        int c = col[e];
        if (wagg[c] > 0.0f) {
            int pos = atomicAdd(&cursor[c], 1);
            srow[pos] = row[e];
        }
    }
}

// ---------------------------------------------------- embW1 = emb @ W1
// 16 vocab rows per block; W1 streamed once per block (33 MB total L2 traffic)
constexpr int RPB = 16;
__global__ void k_embW1(const float* __restrict__ emb, const float* __restrict__ W1,
                        float* __restrict__ embW1) {
    __shared__ float er[RPB][EMB];   // 8 KB
    int t = threadIdx.x;             // 256 threads = output col
    int r0 = blockIdx.x * RPB;
    for (int i = t; i < RPB * EMB; i += 256) {
        er[i / EMB][i % EMB] = emb[(size_t)r0 * EMB + i];
    }
    __syncthreads();
    float acc[RPB];
#pragma unroll
    for (int rr = 0; rr < RPB; rr++) acc[rr] = 0.0f;
    for (int k = 0; k < EMB; k++) {
        float w = W1[k * H1D + t];
#pragma unroll
        for (int rr = 0; rr < RPB; rr++) acc[rr] += er[rr][k] * w;
    }
#pragma unroll
    for (int rr = 0; rr < RPB; rr++) {
        embW1[(size_t)(r0 + rr) * H1D + t] = acc[rr];
    }
}

// -------------------- fused conv1+conv2 over needed nodes:
//   wsum[256] += wagg[v] * relu( b1 + dv^2*embW1[x[v]] + sum_e dinv[r]*dv*embW1[x[r]] )
__global__ void k_fconv(const int* __restrict__ needlist, const int* __restrict__ nneed_p,
                        const float* __restrict__ wagg, const int* __restrict__ x,
                        const int* __restrict__ srow, const int* __restrict__ offs,
                        const int* __restrict__ cnt, const float* __restrict__ dinv,
                        const float* __restrict__ embW1, const float* __restrict__ b1,
                        float* __restrict__ wsum) {
    int lane = threadIdx.x & 63;
    int wib  = threadIdx.x >> 6;                       // wave in block (0..3)
    int wid  = blockIdx.x * (blockDim.x >> 6) + wib;
    int nw   = gridDim.x * (blockDim.x >> 6);
    int nn   = *nneed_p;
    const float4* __restrict__ ew = (const float4*)embW1;   // row r = ew + r*64
    float4 bfrag = ((const float4*)b1)[lane];
    float4 acc2 = {0.0f, 0.0f, 0.0f, 0.0f};

    for (int i = wid; i < nn; i += nw) {
        int v = needlist[i];
        float dv = dinv[v];
        float wa = wagg[v];
        float4 s = ew[(size_t)x[v] * 64 + lane];
        float w0 = dv * dv;
        float4 acc;
        acc.x = bfrag.x + w0 * s.x;
        acc.y = bfrag.y + w0 * s.y;
        acc.z = bfrag.z + w0 * s.z;
        acc.w = bfrag.w + w0 * s.w;
        int start = offs[v], m = cnt[v];
        for (int base = 0; base < m; base += 64) {
            int mm = min(64, m - base);
            int xr = 0; float wr = 0.0f;
            if (lane < mm) {
                int r = srow[start + base + lane];
                xr = x[r];
                wr = dinv[r] * dv;
            }
            int e = 0;
            for (; e + 4 <= mm; e += 4) {
                int i0 = __shfl(xr, e),     i1 = __shfl(xr, e + 1);
                int i2 = __shfl(xr, e + 2), i3 = __shfl(xr, e + 3);
                float q0 = __shfl(wr, e),     q1 = __shfl(wr, e + 1);
                float q2 = __shfl(wr, e + 2), q3 = __shfl(wr, e + 3);
                float4 t0 = ew[(size_t)i0 * 64 + lane];
                float4 t1 = ew[(size_t)i1 * 64 + lane];
                float4 t2 = ew[(size_t)i2 * 64 + lane];
                float4 t3 = ew[(size_t)i3 * 64 + lane];
                acc.x += q0 * t0.x + q1 * t1.x + q2 * t2.x + q3 * t3.x;
                acc.y += q0 * t0.y + q1 * t1.y + q2 * t2.y + q3 * t3.y;
                acc.z += q0 * t0.z + q1 * t1.z + q2 * t2.z + q3 * t3.z;
                acc.w += q0 * t0.w + q1 * t1.w + q2 * t2.w + q3 * t3.w;
            }
            for (; e < mm; e++) {
                int i0 = __shfl(xr, e);
                float q0 = __shfl(wr, e);
                float4 t0 = ew[(size_t)i0 * 64 + lane];
                acc.x += q0 * t0.x;
                acc.y += q0 * t0.y;
                acc.z += q0 * t0.z;
                acc.w += q0 * t0.w;
            }
        }
        acc2.x += wa * fmaxf(acc.x, 0.0f);
        acc2.y += wa * fmaxf(acc.y, 0.0f);
        acc2.z += wa * fmaxf(acc.z, 0.0f);
        acc2.w += wa * fmaxf(acc.w, 0.0f);
    }

    __shared__ float red[4][H1D];
    red[wib][4 * lane + 0] = acc2.x;
    red[wib][4 * lane + 1] = acc2.y;
    red[wib][4 * lane + 2] = acc2.z;
    red[wib][4 * lane + 3] = acc2.w;
    __syncthreads();
    int t = threadIdx.x;
    float ssum = red[0][t] + red[1][t] + red[2][t] + red[3][t];
    atomicAdd(&wsum[t], ssum);
}

// ---------- fused head: zmean = (wsum @ W2)/NP + b2 ; out = zmean @ Wc + bc
// 16 blocks; each block redundantly computes zmean (32 KFLOP) into LDS.
__global__ void k_zout(const float* __restrict__ wsum, const float* __restrict__ W2,
                       const float* __restrict__ b2, const float* __restrict__ Wc,
                       const float* __restrict__ bc, float* __restrict__ out,
                       float inv_np) {
    __shared__ float z[H2D];
    int t = threadIdx.x;
    if (t < H2D) {
        float acc = 0.0f;
#pragma unroll 8
        for (int k = 0; k < H1D; k++) acc += wsum[k] * W2[k * H2D + t];
        z[t] = b2[t] + acc * inv_np;
    }
    __syncthreads();
    int c = blockIdx.x * blockDim.x + t;
    float acc = bc[c];
#pragma unroll 8
    for (int j = 0; j < H2D; j++) acc += z[j] * Wc[(size_t)j * VOC + c];
    out[c] = acc;
}

extern "C" void kernel_launch(void* const* d_in, const int* in_sizes, int n_in,
                              void* d_out, int out_size, void* d_ws, size_t ws_size,
                              hipStream_t stream) {
    const int n  = in_sizes[0];
    const int ne = in_sizes[1] / 2;
    const int np = in_sizes[2];

    const int*   x    = (const int*)d_in[0];
    const int*   ei   = (const int*)d_in[1];
    const int*   xpos = (const int*)d_in[2];
    const float* emb  = (const float*)d_in[3];
    const float* W1   = (const float*)d_in[4];
    const float* b1   = (const float*)d_in[5];
    const float* W2   = (const float*)d_in[6];
    const float* b2   = (const float*)d_in[7];
    const float* Wc   = (const float*)d_in[8];
    const float* bc   = (const float*)d_in[9];
    float*       out  = (float*)d_out;

    const int* row = ei;       // edge_index[0]
    const int* col = ei + ne;  // edge_index[1]

    char* p = (char*)d_ws;
    auto alloc = [&](size_t bytes) {
        char* r = p;
        p += (bytes + 255) & ~(size_t)255;
        return r;
    };
    int*   cnt      = (int*)alloc((size_t)n * 4);
    int*   offs     = (int*)alloc((size_t)n * 4);
    int*   cursor   = (int*)alloc((size_t)n * 4);
    int*   count    = (int*)alloc((size_t)n * 4);
    int*   needlist = (int*)alloc((size_t)n * 4);
    int*   srow     = (int*)alloc((size_t)ne * 4);
    int*   nflag    = (int*)alloc(256 * 4);
    int*   total    = (int*)alloc(256 * 4);
    float* dinv     = (float*)alloc((size_t)n * 4);
    float* wagg     = (float*)alloc((size_t)n * 4);
    float* embW1    = (float*)alloc((size_t)VOC * H1D * 4);
    float* wsum     = (float*)alloc(H1D * 4);

    const int nb  = (n + 255) / 256;
    const int neb = (ne + 255) / 256;

    k_init<<<nb, 256, 0, stream>>>(cnt, count, wsum, nflag, total, n);
    k_histcnt<<<neb, 256, 0, stream>>>(col, xpos, cnt, count, ne, np);
    k_dinv<<<nb, 256, 0, stream>>>(cnt, count, dinv, wagg, n);
    k_waggE<<<neb, 256, 0, stream>>>(row, col, count, dinv, wagg, ne);
    k_alloc<<<nb, 256, 0, stream>>>(wagg, cnt, needlist, nflag, total, offs, cursor, n);
    k_scatter<<<neb, 256, 0, stream>>>(row, col, wagg, cursor, srow, ne);
    k_embW1<<<VOC / RPB, 256, 0, stream>>>(emb, W1, embW1);
    k_fconv<<<512, 256, 0, stream>>>(needlist, nflag, wagg, x, srow, offs, cnt,
                                     dinv, embW1, b1, wsum);
    k_zout<<<VOC / 256, 256, 0, stream>>>(wsum, W2, b2, Wc, bc, out, 1.0f / (float)np);
}

// Round 5
// 198.889 us; speedup vs baseline: 1.1472x; 1.0944x over previous
//
#include <hip/hip_runtime.h>

constexpr int EMB  = 128;   // EMB_DIM
constexpr int H1D  = 256;   // 2*HIDDEN
constexpr int H2D  = 128;   // HIDDEN
constexpr int VOC  = 4096;  // VOCAB
constexpr int NSL  = 32;    // wsum slices (atomic-contention spreading)

// ---------------------------------------------------------------- init
__global__ void k_init(int* cnt, int* count, float* wsum, int* nflag, int* total, int n) {
    int i = blockIdx.x * blockDim.x + threadIdx.x;
    if (i < n) { cnt[i] = 0; count[i] = 0; }
    if (i < NSL * H1D) wsum[i] = 0.0f;
    if (i == 0) { *nflag = 0; *total = 0; }
}

// --------------------- fused: in-degree histogram + x_position multiplicity
__global__ void k_histcnt(const int* __restrict__ col, const int* __restrict__ xpos,
                          int* cnt, int* count, int ne, int np) {
    int e = blockIdx.x * blockDim.x + threadIdx.x;
    if (e < ne) atomicAdd(&cnt[col[e]], 1);
    if (e < np) atomicAdd(&count[xpos[e]], 1);
}

// ---------------- wagg edge contributions: wagg[row] += count[col]*dinv[col]*dinv[row]
// dinv computed on the fly from cnt. wagg was zeroed... no: wagg is UNINITIALIZED ws.
// We zero it here? No — wagg must be zeroed before these atomics: do it in k_init? k_init
// is one pass over n already; add wagg zeroing there (see k_init2 below).
__global__ void k_waggE(const int* __restrict__ row, const int* __restrict__ col,
                        const int* __restrict__ count, const int* __restrict__ cnt,
                        float* wagg, int ne) {
    int e = blockIdx.x * blockDim.x + threadIdx.x;
    if (e < ne) {
        int c = col[e];
        int cc = count[c];
        if (cc > 0) {
            int r = row[e];
            float dc = rsqrtf((float)cnt[c] + 1.0f);
            float dr = rsqrtf((float)cnt[r] + 1.0f);
            atomicAdd(&wagg[r], (float)cc * dc * dr);
        }
    }
}

// ------- alloc: finalize wagg (+self term), needlist append, CSR bump-alloc.
// Wave-aggregated atomics: 2 atomics per wave.
__global__ void k_alloc(float* wagg, const int* __restrict__ cnt,
                        const int* __restrict__ count,
                        int* needlist, int* nflag, int* total,
                        int* offs, int* cursor, int n) {
    int v = blockIdx.x * blockDim.x + threadIdx.x;
    int lane = threadIdx.x & 63;
    float wa = 0.0f;
    int cv = 0;
    bool need = false;
    if (v < n) {
        wa = wagg[v];
        int cc = count[v];
        cv = cnt[v];
        if (cc > 0) {
            float d2 = 1.0f / ((float)cv + 1.0f);   // dinv^2
            wa += (float)cc * d2;
        }
        need = (wa > 0.0f);
        if (need) wagg[v] = wa;                      // finalized weight
    }
    int seg = need ? cv : 0;
    // wave-inclusive scan of seg
    int incl = seg;
#pragma unroll
    for (int d = 1; d < 64; d <<= 1) {
        int t = __shfl_up(incl, d);
        if (lane >= d) incl += t;
    }
    int excl = incl - seg;
    int wave_total = __shfl(incl, 63);
    unsigned long long mask = __ballot(need);
    int rank = __popcll(mask & ((1ull << lane) - 1));
    int wcnt = __popcll(mask);
    int base_id = 0, base_off = 0;
    if (lane == 0) {
        if (wcnt > 0) base_id = atomicAdd(nflag, wcnt);
        if (wave_total > 0) base_off = atomicAdd(total, wave_total);
    }
    base_id  = __shfl(base_id, 0);
    base_off = __shfl(base_off, 0);
    if (need) {
        needlist[base_id + rank] = v;
        int o = base_off + excl;
        offs[v] = o;
        cursor[v] = o;
    }
}

// ---------------- scatter (filtered): only edges whose col is needed.
// Stores x[row] and dinv[row] directly — kills two dependent gather hops in fconv.
__global__ void k_scatter(const int* __restrict__ row, const int* __restrict__ col,
                          const float* __restrict__ wagg, const int* __restrict__ x,
                          const int* __restrict__ cnt,
                          int* cursor, int* srowx, float* srowd, int ne) {
    int e = blockIdx.x * blockDim.x + threadIdx.x;
    if (e < ne) {
        int c = col[e];
        if (wagg[c] > 0.0f) {
            int r = row[e];
            int pos = atomicAdd(&cursor[c], 1);
            srowx[pos] = x[r];
            srowd[pos] = rsqrtf((float)cnt[r] + 1.0f);
        }
    }
}

// ---------------------------------------------------- embW1 = emb @ W1
constexpr int RPB = 16;
__global__ void k_embW1(const float* __restrict__ emb, const float* __restrict__ W1,
                        float* __restrict__ embW1) {
    __shared__ float er[RPB][EMB];   // 8 KB
    int t = threadIdx.x;
    int r0 = blockIdx.x * RPB;
    for (int i = t; i < RPB * EMB; i += 256) {
        er[i / EMB][i % EMB] = emb[(size_t)r0 * EMB + i];
    }
    __syncthreads();
    float acc[RPB];
#pragma unroll
    for (int rr = 0; rr < RPB; rr++) acc[rr] = 0.0f;
    for (int k = 0; k < EMB; k++) {
        float w = W1[k * H1D + t];
#pragma unroll
        for (int rr = 0; rr < RPB; rr++) acc[rr] += er[rr][k] * w;
    }
#pragma unroll
    for (int rr = 0; rr < RPB; rr++) {
        embW1[(size_t)(r0 + rr) * H1D + t] = acc[rr];
    }
}

// -------------------- fused conv1+conv2 over needed nodes (one wave/node, grid-stride):
//   wsum += wagg[v] * relu( b1 + dv^2*embW1[x[v]] + sum_e srowd[e]*dv*embW1[srowx[e]] )
__global__ void k_fconv(const int* __restrict__ needlist, const int* __restrict__ nneed_p,
                        const float* __restrict__ wagg, const int* __restrict__ x,
                        const int* __restrict__ srowx, const float* __restrict__ srowd,
                        const int* __restrict__ offs, const int* __restrict__ cnt,
                        const float* __restrict__ embW1, const float* __restrict__ b1,
                        float* __restrict__ wsum) {
    int lane = threadIdx.x & 63;
    int wib  = threadIdx.x >> 6;
    int wid  = blockIdx.x * (blockDim.x >> 6) + wib;
    int nw   = gridDim.x * (blockDim.x >> 6);
    int nn   = *nneed_p;
    const float4* __restrict__ ew = (const float4*)embW1;   // row r = ew + r*64
    float4 bfrag = ((const float4*)b1)[lane];
    float4 acc2 = {0.0f, 0.0f, 0.0f, 0.0f};

    for (int i = wid; i < nn; i += nw) {
        int v = needlist[i];
        int cv = cnt[v];
        float dv = rsqrtf((float)cv + 1.0f);
        float wa = wagg[v];
        float4 s = ew[(size_t)x[v] * 64 + lane];
        float w0 = dv * dv;
        float4 acc;
        acc.x = bfrag.x + w0 * s.x;
        acc.y = bfrag.y + w0 * s.y;
        acc.z = bfrag.z + w0 * s.z;
        acc.w = bfrag.w + w0 * s.w;
        int start = offs[v], m = cv;
        for (int base = 0; base < m; base += 64) {
            int mm = min(64, m - base);
            int xr = 0; float wr = 0.0f;
            if (lane < mm) {
                xr = srowx[start + base + lane];          // independent loads,
                wr = srowd[start + base + lane] * dv;     // no dependent chain
            }
            int e = 0;
            for (; e + 4 <= mm; e += 4) {
                int i0 = __shfl(xr, e),     i1 = __shfl(xr, e + 1);
                int i2 = __shfl(xr, e + 2), i3 = __shfl(xr, e + 3);
                float q0 = __shfl(wr, e),     q1 = __shfl(wr, e + 1);
                float q2 = __shfl(wr, e + 2), q3 = __shfl(wr, e + 3);
                float4 t0 = ew[(size_t)i0 * 64 + lane];
                float4 t1 = ew[(size_t)i1 * 64 + lane];
                float4 t2 = ew[(size_t)i2 * 64 + lane];
                float4 t3 = ew[(size_t)i3 * 64 + lane];
                acc.x += q0 * t0.x + q1 * t1.x + q2 * t2.x + q3 * t3.x;
                acc.y += q0 * t0.y + q1 * t1.y + q2 * t2.y + q3 * t3.y;
                acc.z += q0 * t0.z + q1 * t1.z + q2 * t2.z + q3 * t3.z;
                acc.w += q0 * t0.w + q1 * t1.w + q2 * t2.w + q3 * t3.w;
            }
            for (; e < mm; e++) {
                int i0 = __shfl(xr, e);
                float q0 = __shfl(wr, e);
                float4 t0 = ew[(size_t)i0 * 64 + lane];
                acc.x += q0 * t0.x;
                acc.y += q0 * t0.y;
                acc.z += q0 * t0.z;
                acc.w += q0 * t0.w;
            }
        }
        acc2.x += wa * fmaxf(acc.x, 0.0f);
        acc2.y += wa * fmaxf(acc.y, 0.0f);
        acc2.z += wa * fmaxf(acc.z, 0.0f);
        acc2.w += wa * fmaxf(acc.w, 0.0f);
    }

    __shared__ float red[4][H1D];
    red[wib][4 * lane + 0] = acc2.x;
    red[wib][4 * lane + 1] = acc2.y;
    red[wib][4 * lane + 2] = acc2.z;
    red[wib][4 * lane + 3] = acc2.w;
    __syncthreads();
    int t = threadIdx.x;
    float ssum = red[0][t] + red[1][t] + red[2][t] + red[3][t];
    // slice by block to bound same-address contention at gridDim/NSL
    atomicAdd(&wsum[(blockIdx.x & (NSL - 1)) * H1D + t], ssum);
}

// ---------- fused head: reduce wsum slices; zmean = (wsum @ W2)/NP + b2; out = zmean @ Wc + bc
__global__ void k_zout(const float* __restrict__ wsum, const float* __restrict__ W2,
                       const float* __restrict__ b2, const float* __restrict__ Wc,
                       const float* __restrict__ bc, float* __restrict__ out,
                       float inv_np) {
    __shared__ float ws[H1D];
    __shared__ float z[H2D];
    int t = threadIdx.x;
    float s = 0.0f;
#pragma unroll
    for (int c = 0; c < NSL; c++) s += wsum[c * H1D + t];
    ws[t] = s;
    __syncthreads();
    if (t < H2D) {
        float acc = 0.0f;
#pragma unroll 8
        for (int k = 0; k < H1D; k++) acc += ws[k] * W2[k * H2D + t];
        z[t] = b2[t] + acc * inv_np;
    }
    __syncthreads();
    int c = blockIdx.x * blockDim.x + t;
    float acc = bc[c];
#pragma unroll 8
    for (int j = 0; j < H2D; j++) acc += z[j] * Wc[(size_t)j * VOC + c];
    out[c] = acc;
}

extern "C" void kernel_launch(void* const* d_in, const int* in_sizes, int n_in,
                              void* d_out, int out_size, void* d_ws, size_t ws_size,
                              hipStream_t stream) {
    const int n  = in_sizes[0];
    const int ne = in_sizes[1] / 2;
    const int np = in_sizes[2];

    const int*   x    = (const int*)d_in[0];
    const int*   ei   = (const int*)d_in[1];
    const int*   xpos = (const int*)d_in[2];
    const float* emb  = (const float*)d_in[3];
    const float* W1   = (const float*)d_in[4];
    const float* b1   = (const float*)d_in[5];
    const float* W2   = (const float*)d_in[6];
    const float* b2   = (const float*)d_in[7];
    const float* Wc   = (const float*)d_in[8];
    const float* bc   = (const float*)d_in[9];
    float*       out  = (float*)d_out;

    const int* row = ei;       // edge_index[0]
    const int* col = ei + ne;  // edge_index[1]

    char* p = (char*)d_ws;
    auto alloc = [&](size_t bytes) {
        char* r = p;
        p += (bytes + 255) & ~(size_t)255;
        return r;
    };
    int*   cnt      = (int*)alloc((size_t)n * 4);
    int*   offs     = (int*)alloc((size_t)n * 4);
    int*   cursor   = (int*)alloc((size_t)n * 4);
    int*   count    = (int*)alloc((size_t)n * 4);
    int*   needlist = (int*)alloc((size_t)n * 4);
    int*   srowx    = (int*)alloc((size_t)ne * 4);
    float* srowd    = (float*)alloc((size_t)ne * 4);
    int*   nflag    = (int*)alloc(256 * 4);
    int*   total    = (int*)alloc(256 * 4);
    float* wagg     = (float*)alloc((size_t)n * 4);
    float* embW1    = (float*)alloc((size_t)VOC * H1D * 4);
    float* wsum     = (float*)alloc((size_t)NSL * H1D * 4);

    const int nb  = (n + 255) / 256;
    const int neb = (ne + 255) / 256;

    // zero wagg via memset (async, graph-safe) — k_init covers the rest
    hipMemsetAsync(wagg, 0, (size_t)n * 4, stream);
    k_init<<<nb, 256, 0, stream>>>(cnt, count, wsum, nflag, total, n);
    k_histcnt<<<neb, 256, 0, stream>>>(col, xpos, cnt, count, ne, np);
    k_waggE<<<neb, 256, 0, stream>>>(row, col, count, cnt, wagg, ne);
    k_alloc<<<nb, 256, 0, stream>>>(wagg, cnt, count, needlist, nflag, total, offs, cursor, n);
    k_scatter<<<neb, 256, 0, stream>>>(row, col, wagg, x, cnt, cursor, srowx, srowd, ne);
    k_embW1<<<VOC / RPB, 256, 0, stream>>>(emb, W1, embW1);
    k_fconv<<<2048, 256, 0, stream>>>(needlist, nflag, wagg, x, srowx, srowd, offs, cnt,
                                      embW1, b1, wsum);
    k_zout<<<VOC / 256, 256, 0, stream>>>(wsum, W2, b2, Wc, bc, out, 1.0f / (float)np);
}

// Round 7
// 194.583 us; speedup vs baseline: 1.1726x; 1.0221x over previous
//
#include <hip/hip_runtime.h>

constexpr int EMB  = 128;   // EMB_DIM
constexpr int H1D  = 256;   // 2*HIDDEN
constexpr int H2D  = 128;   // HIDDEN
constexpr int VOC  = 4096;  // VOCAB
constexpr int NSL  = 32;    // wsum slices (atomic-contention spreading)

// ---------------- init: zero cnt, count, needed-bitmask, wagg, wsum, counters
__global__ void k_init(int* cnt, int* count, unsigned int* needed, float* wagg,
                       float* wsum, int* nflag, int* total, int n, int nwords) {
    int i = blockIdx.x * blockDim.x + threadIdx.x;
    if (i < n) { cnt[i] = 0; count[i] = 0; wagg[i] = 0.0f; }
    if (i < nwords) needed[i] = 0u;
    if (i < NSL * H1D) wsum[i] = 0.0f;
    if (i == 0) { *nflag = 0; *total = 0; }
}

// ---------------- x_position multiplicities (count must be final before k_hist)
__global__ void k_count(const int* __restrict__ xpos, int* count, int np) {
    int p = blockIdx.x * blockDim.x + threadIdx.x;
    if (p < np) atomicAdd(&count[xpos[p]], 1);
}

// ---------------- in-degree histogram + needed-row mark (atomicOr — no plain-store race)
__global__ void k_hist(const int* __restrict__ row, const int* __restrict__ col,
                       const int* __restrict__ count, int* cnt,
                       unsigned int* needed, int ne) {
    int e = blockIdx.x * blockDim.x + threadIdx.x;
    if (e < ne) {
        int c = col[e];
        atomicAdd(&cnt[c], 1);
        if (count[c] > 0) {                     // ~2% of edges
            int r = row[e];
            atomicOr(&needed[r >> 5], 1u << (r & 31));
        }
    }
}

// ------- alloc: need = bit||flagged; needb canonical byte; CSR bump-alloc;
//         wagg self term (plain own-thread write). Wave-aggregated atomics.
__global__ void k_alloc(const unsigned int* __restrict__ needed,
                        const int* __restrict__ cnt, const int* __restrict__ count,
                        float* wagg, int* needb,
                        int* needlist, int* nflag, int* total,
                        int* offs, int* cursor, int n) {
    int v = blockIdx.x * blockDim.x + threadIdx.x;
    int lane = threadIdx.x & 63;
    int cv = 0;
    bool need = false;
    if (v < n) {
        cv = cnt[v];
        int cc = count[v];
        bool bit = (needed[v >> 5] >> (v & 31)) & 1u;
        bool flag = (cc > 0);
        need = bit || flag;
        needb[v] = need ? 1 : 0;
        if (flag) wagg[v] = (float)cc / ((float)cv + 1.0f);   // count[v]*dinv[v]^2
    }
    int seg = need ? cv : 0;
    // wave-inclusive scan of seg (proven R5 body)
    int incl = seg;
#pragma unroll
    for (int d = 1; d < 64; d <<= 1) {
        int t = __shfl_up(incl, d);
        if (lane >= d) incl += t;
    }
    int excl = incl - seg;
    int wave_total = __shfl(incl, 63);
    unsigned long long mask = __ballot(need);
    int rank = __popcll(mask & ((1ull << lane) - 1));
    int wcnt = __popcll(mask);
    int base_id = 0, base_off = 0;
    if (lane == 0) {
        if (wcnt > 0) base_id = atomicAdd(nflag, wcnt);
        if (wave_total > 0) base_off = atomicAdd(total, wave_total);
    }
    base_id  = __shfl(base_id, 0);
    base_off = __shfl(base_off, 0);
    if (need) {
        needlist[base_id + rank] = v;
        int o = base_off + excl;
        offs[v] = o;
        cursor[v] = o;
    }
}

// ---------------- scatter (filtered to needed cols): store x[row], dinv[row];
//                  fold wagg edge terms in (count/cnt final here, ~16k atomics).
__global__ void k_scatter(const int* __restrict__ row, const int* __restrict__ col,
                          const int* __restrict__ needb, const int* __restrict__ count,
                          const int* __restrict__ x, const int* __restrict__ cnt,
                          int* cursor, int* srowx, float* srowd, float* wagg, int ne) {
    int e = blockIdx.x * blockDim.x + threadIdx.x;
    if (e < ne) {
        int c = col[e];
        if (needb[c]) {
            int r = row[e];
            int pos = atomicAdd(&cursor[c], 1);
            float dr = rsqrtf((float)cnt[r] + 1.0f);
            srowx[pos] = x[r];
            srowd[pos] = dr;
            int cc = count[c];
            if (cc > 0) {
                float dc = rsqrtf((float)cnt[c] + 1.0f);
                atomicAdd(&wagg[r], (float)cc * dc * dr);
            }
        }
    }
}

// ---------------------------------------------------- embW1 = emb @ W1 (proven)
constexpr int RPB = 16;
__global__ void k_embW1(const float* __restrict__ emb, const float* __restrict__ W1,
                        float* __restrict__ embW1) {
    __shared__ float er[RPB][EMB];   // 8 KB
    int t = threadIdx.x;
    int r0 = blockIdx.x * RPB;
    for (int i = t; i < RPB * EMB; i += 256) {
        er[i / EMB][i % EMB] = emb[(size_t)r0 * EMB + i];
    }
    __syncthreads();
    float acc[RPB];
#pragma unroll
    for (int rr = 0; rr < RPB; rr++) acc[rr] = 0.0f;
    for (int k = 0; k < EMB; k++) {
        float w = W1[k * H1D + t];
#pragma unroll
        for (int rr = 0; rr < RPB; rr++) acc[rr] += er[rr][k] * w;
    }
#pragma unroll
    for (int rr = 0; rr < RPB; rr++) {
        embW1[(size_t)(r0 + rr) * H1D + t] = acc[rr];
    }
}

// -------------------- fused conv1+conv2 over needed nodes (proven R5 body):
//   wsum += wagg[v] * relu( b1 + dv^2*embW1[x[v]] + sum_e srowd[e]*dv*embW1[srowx[e]] )
__global__ void k_fconv(const int* __restrict__ needlist, const int* __restrict__ nneed_p,
                        const float* __restrict__ wagg, const int* __restrict__ x,
                        const int* __restrict__ srowx, const float* __restrict__ srowd,
                        const int* __restrict__ offs, const int* __restrict__ cnt,
                        const float* __restrict__ embW1, const float* __restrict__ b1,
                        float* __restrict__ wsum) {
    int lane = threadIdx.x & 63;
    int wib  = threadIdx.x >> 6;
    int wid  = blockIdx.x * (blockDim.x >> 6) + wib;
    int nw   = gridDim.x * (blockDim.x >> 6);
    int nn   = *nneed_p;
    const float4* __restrict__ ew = (const float4*)embW1;   // row r = ew + r*64
    float4 bfrag = ((const float4*)b1)[lane];
    float4 acc2 = {0.0f, 0.0f, 0.0f, 0.0f};

    for (int i = wid; i < nn; i += nw) {
        int v = needlist[i];
        int cv = cnt[v];
        float dv = rsqrtf((float)cv + 1.0f);
        float wa = wagg[v];
        float4 s = ew[(size_t)x[v] * 64 + lane];
        float w0 = dv * dv;
        float4 acc;
        acc.x = bfrag.x + w0 * s.x;
        acc.y = bfrag.y + w0 * s.y;
        acc.z = bfrag.z + w0 * s.z;
        acc.w = bfrag.w + w0 * s.w;
        int start = offs[v], m = cv;
        for (int base = 0; base < m; base += 64) {
            int mm = min(64, m - base);
            int xr = 0; float wr = 0.0f;
            if (lane < mm) {
                xr = srowx[start + base + lane];
                wr = srowd[start + base + lane] * dv;
            }
            int e = 0;
            for (; e + 4 <= mm; e += 4) {
                int i0 = __shfl(xr, e),     i1 = __shfl(xr, e + 1);
                int i2 = __shfl(xr, e + 2), i3 = __shfl(xr, e + 3);
                float q0 = __shfl(wr, e),     q1 = __shfl(wr, e + 1);
                float q2 = __shfl(wr, e + 2), q3 = __shfl(wr, e + 3);
                float4 t0 = ew[(size_t)i0 * 64 + lane];
                float4 t1 = ew[(size_t)i1 * 64 + lane];
                float4 t2 = ew[(size_t)i2 * 64 + lane];
                float4 t3 = ew[(size_t)i3 * 64 + lane];
                acc.x += q0 * t0.x + q1 * t1.x + q2 * t2.x + q3 * t3.x;
                acc.y += q0 * t0.y + q1 * t1.y + q2 * t2.y + q3 * t3.y;
                acc.z += q0 * t0.z + q1 * t1.z + q2 * t2.z + q3 * t3.z;
                acc.w += q0 * t0.w + q1 * t1.w + q2 * t2.w + q3 * t3.w;
            }
            for (; e < mm; e++) {
                int i0 = __shfl(xr, e);
                float q0 = __shfl(wr, e);
                float4 t0 = ew[(size_t)i0 * 64 + lane];
                acc.x += q0 * t0.x;
                acc.y += q0 * t0.y;
                acc.z += q0 * t0.z;
                acc.w += q0 * t0.w;
            }
        }
        acc2.x += wa * fmaxf(acc.x, 0.0f);
        acc2.y += wa * fmaxf(acc.y, 0.0f);
        acc2.z += wa * fmaxf(acc.z, 0.0f);
        acc2.w += wa * fmaxf(acc.w, 0.0f);
    }

    __shared__ float red[4][H1D];
    red[wib][4 * lane + 0] = acc2.x;
    red[wib][4 * lane + 1] = acc2.y;
    red[wib][4 * lane + 2] = acc2.z;
    red[wib][4 * lane + 3] = acc2.w;
    __syncthreads();
    int t = threadIdx.x;
    float ssum = red[0][t] + red[1][t] + red[2][t] + red[3][t];
    atomicAdd(&wsum[(blockIdx.x & (NSL - 1)) * H1D + t], ssum);
}

// ---------- fused head (proven): reduce slices; zmean = (wsum@W2)/NP + b2; out = zmean@Wc + bc
__global__ void k_zout(const float* __restrict__ wsum, const float* __restrict__ W2,
                       const float* __restrict__ b2, const float* __restrict__ Wc,
                       const float* __restrict__ bc, float* __restrict__ out,
                       float inv_np) {
    __shared__ float ws[H1D];
    __shared__ float z[H2D];
    int t = threadIdx.x;
    float s = 0.0f;
#pragma unroll
    for (int c = 0; c < NSL; c++) s += wsum[c * H1D + t];
    ws[t] = s;
    __syncthreads();
    if (t < H2D) {
        float acc = 0.0f;
#pragma unroll 8
        for (int k = 0; k < H1D; k++) acc += ws[k] * W2[k * H2D + t];
        z[t] = b2[t] + acc * inv_np;
    }
    __syncthreads();
    int c = blockIdx.x * blockDim.x + t;
    float acc = bc[c];
#pragma unroll 8
    for (int j = 0; j < H2D; j++) acc += z[j] * Wc[(size_t)j * VOC + c];
    out[c] = acc;
}

extern "C" void kernel_launch(void* const* d_in, const int* in_sizes, int n_in,
                              void* d_out, int out_size, void* d_ws, size_t ws_size,
                              hipStream_t stream) {
    const int n  = in_sizes[0];
    const int ne = in_sizes[1] / 2;
    const int np = in_sizes[2];

    const int*   x    = (const int*)d_in[0];
    const int*   ei   = (const int*)d_in[1];
    const int*   xpos = (const int*)d_in[2];
    const float* emb  = (const float*)d_in[3];
    const float* W1   = (const float*)d_in[4];
    const float* b1   = (const float*)d_in[5];
    const float* W2   = (const float*)d_in[6];
    const float* b2   = (const float*)d_in[7];
    const float* Wc   = (const float*)d_in[8];
    const float* bc   = (const float*)d_in[9];
    float*       out  = (float*)d_out;

    const int* row = ei;       // edge_index[0]
    const int* col = ei + ne;  // edge_index[1]

    char* p = (char*)d_ws;
    auto alloc = [&](size_t bytes) {
        char* r = p;
        p += (bytes + 255) & ~(size_t)255;
        return r;
    };
    int*          cnt      = (int*)alloc((size_t)n * 4);
    int*          offs     = (int*)alloc((size_t)n * 4);
    int*          cursor   = (int*)alloc((size_t)n * 4);
    int*          count    = (int*)alloc((size_t)n * 4);
    int*          needb    = (int*)alloc((size_t)n * 4);
    int*          needlist = (int*)alloc((size_t)n * 4);
    unsigned int* needed   = (unsigned int*)alloc((size_t)((n + 31) / 32) * 4);
    int*          srowx    = (int*)alloc((size_t)ne * 4);
    float*        srowd    = (float*)alloc((size_t)ne * 4);
    int*          nflag    = (int*)alloc(256 * 4);
    int*          total    = (int*)alloc(256 * 4);
    float*        wagg     = (float*)alloc((size_t)n * 4);
    float*        embW1    = (float*)alloc((size_t)VOC * H1D * 4);
    float*        wsum     = (float*)alloc((size_t)NSL * H1D * 4);

    const int nb     = (n + 255) / 256;
    const int neb    = (ne + 255) / 256;
    const int nwords = (n + 31) / 32;

    k_init<<<nb, 256, 0, stream>>>(cnt, count, needed, wagg, wsum, nflag, total, n, nwords);
    k_count<<<(np + 255) / 256, 256, 0, stream>>>(xpos, count, np);
    k_hist<<<neb, 256, 0, stream>>>(row, col, count, cnt, needed, ne);
    k_alloc<<<nb, 256, 0, stream>>>(needed, cnt, count, wagg, needb,
                                    needlist, nflag, total, offs, cursor, n);
    k_scatter<<<neb, 256, 0, stream>>>(row, col, needb, count, x, cnt,
                                       cursor, srowx, srowd, wagg, ne);
    k_embW1<<<VOC / RPB, 256, 0, stream>>>(emb, W1, embW1);
    k_fconv<<<2048, 256, 0, stream>>>(needlist, nflag, wagg, x, srowx, srowd, offs, cnt,
                                      embW1, b1, wsum);
    k_zout<<<VOC / 256, 256, 0, stream>>>(wsum, W2, b2, Wc, bc, out, 1.0f / (float)np);
}

// Round 8
// 192.592 us; speedup vs baseline: 1.1847x; 1.0103x over previous
//
#include <hip/hip_runtime.h>

constexpr int EMB  = 128;   // EMB_DIM
constexpr int H1D  = 256;   // 2*HIDDEN
constexpr int H2D  = 128;   // HIDDEN
constexpr int VOC  = 4096;  // VOCAB
constexpr int NSL  = 32;    // wsum slices (atomic-contention spreading)

// ---------------- init: zero cnt, count, flagbits, markbits, wagg, wsum, counters
__global__ void k_init(int* cnt, int* count, unsigned int* flagbits, unsigned int* markw,
                       float* wagg, float* wsum, int* nflag, int* total,
                       int n, int nwords) {
    int i = blockIdx.x * blockDim.x + threadIdx.x;
    if (i < n) { cnt[i] = 0; count[i] = 0; wagg[i] = 0.0f; }
    if (i < nwords) { flagbits[i] = 0u; markw[i] = 0u; }
    if (i < NSL * H1D) wsum[i] = 0.0f;
    if (i == 0) { *nflag = 0; *total = 0; }
}

// ---------------- embW1 = emb @ W1 (blocks 0..255); block 256: count + flagbits
constexpr int RPB = 16;
__global__ void k_embW1C(const float* __restrict__ emb, const float* __restrict__ W1,
                         float* __restrict__ embW1,
                         const int* __restrict__ xpos, int* count,
                         unsigned int* flagbits, int np) {
    int t = threadIdx.x;
    if (blockIdx.x == VOC / RPB) {   // extra block: x_position multiplicities + flag mask
        for (int p = t; p < np; p += blockDim.x) {
            int v = xpos[p];
            atomicAdd(&count[v], 1);
            atomicOr(&flagbits[v >> 5], 1u << (v & 31));
        }
        return;
    }
    __shared__ float er[RPB][EMB];   // 8 KB
    int r0 = blockIdx.x * RPB;
    for (int i = t; i < RPB * EMB; i += 256) {
        er[i / EMB][i % EMB] = emb[(size_t)r0 * EMB + i];
    }
    __syncthreads();
    float acc[RPB];
#pragma unroll
    for (int rr = 0; rr < RPB; rr++) acc[rr] = 0.0f;
    for (int k = 0; k < EMB; k++) {
        float w = W1[k * H1D + t];
#pragma unroll
        for (int rr = 0; rr < RPB; rr++) acc[rr] += er[rr][k] * w;
    }
#pragma unroll
    for (int rr = 0; rr < RPB; rr++) {
        embW1[(size_t)(r0 + rr) * H1D + t] = acc[rr];
    }
}

// ---------------- in-degree histogram + needed-row mark.
// Flag test hits the 6.25 KB L1-resident bitmask, not a 200 KB table.
__global__ void k_hist(const int* __restrict__ row, const int* __restrict__ col,
                       const unsigned int* __restrict__ flagbits, int* cnt,
                       unsigned int* markw, int ne) {
    int e = blockIdx.x * blockDim.x + threadIdx.x;
    if (e < ne) {
        int c = col[e];
        atomicAdd(&cnt[c], 1);
        if ((flagbits[c >> 5] >> (c & 31)) & 1u) {     // ~2% of edges
            int r = row[e];
            atomicOr(&markw[r >> 5], 1u << (r & 31));
        }
    }
}

// ------- alloc: need = mark||flag; canonical needbits via wave-ballot plain store
//         (each 32-bit word owned by exactly one wave — race-free);
//         CSR bump-alloc (wave-aggregated atomics); wagg self term.
__global__ void k_alloc(unsigned int* needw,                  // in: marks, out: canonical
                        const unsigned int* __restrict__ flagbits,
                        const int* __restrict__ cnt, const int* __restrict__ count,
                        float* wagg, int* needlist, int* nflag, int* total,
                        int* offs, int* cursor, int n) {
    int v = blockIdx.x * blockDim.x + threadIdx.x;
    int lane = threadIdx.x & 63;
    int cv = 0;
    bool need = false;
    if (v < n) {
        cv = cnt[v];
        bool mark = (needw[v >> 5] >> (v & 31)) & 1u;
        bool flag = (flagbits[v >> 5] >> (v & 31)) & 1u;
        need = mark || flag;
        if (flag) wagg[v] = (float)count[v] / ((float)cv + 1.0f);  // count*dinv^2
    }
    // canonical needbits: ballot → one word per half-wave, plain store by owner lane
    unsigned long long nm = __ballot(need);
    int wbase = (v & ~63) >> 5;            // v is wave-aligned at lane 0
    if (lane == 0)  needw[wbase]     = (unsigned int)(nm & 0xffffffffu);
    if (lane == 32) needw[wbase + 1] = (unsigned int)(nm >> 32);
    int seg = need ? cv : 0;
    // wave-inclusive scan of seg (proven body)
    int incl = seg;
#pragma unroll
    for (int d = 1; d < 64; d <<= 1) {
        int t = __shfl_up(incl, d);
        if (lane >= d) incl += t;
    }
    int excl = incl - seg;
    int wave_total = __shfl(incl, 63);
    int rank = __popcll(nm & ((1ull << lane) - 1));
    int wcnt = __popcll(nm);
    int base_id = 0, base_off = 0;
    if (lane == 0) {
        if (wcnt > 0) base_id = atomicAdd(nflag, wcnt);
        if (wave_total > 0) base_off = atomicAdd(total, wave_total);
    }
    base_id  = __shfl(base_id, 0);
    base_off = __shfl(base_off, 0);
    if (need) {
        needlist[base_id + rank] = v;
        int o = base_off + excl;
        offs[v] = o;
        cursor[v] = o;
    }
}

// ---------------- scatter (filtered to needed cols via L1-resident bitmask):
//   store packed {x[row], dinv[row]}; fold wagg edge terms (flagged edges only).
__global__ void k_scatter(const int* __restrict__ row, const int* __restrict__ col,
                          const unsigned int* __restrict__ needw,
                          const unsigned int* __restrict__ flagbits,
                          const int* __restrict__ count,
                          const int* __restrict__ x, const int* __restrict__ cnt,
                          int* cursor, int2* srowp, float* wagg, int ne) {
    int e = blockIdx.x * blockDim.x + threadIdx.x;
    if (e < ne) {
        int c = col[e];
        if ((needw[c >> 5] >> (c & 31)) & 1u) {
            int r = row[e];
            int pos = atomicAdd(&cursor[c], 1);
            float dr = rsqrtf((float)cnt[r] + 1.0f);
            int2 pk; pk.x = x[r]; pk.y = __float_as_int(dr);
            srowp[pos] = pk;
            if ((flagbits[c >> 5] >> (c & 31)) & 1u) {    // ~2% of edges
                float dc = rsqrtf((float)cnt[c] + 1.0f);
                atomicAdd(&wagg[r], (float)count[c] * dc * dr);
            }
        }
    }
}

// -------------------- fused conv1+conv2 over needed nodes (proven body, packed loads):
//   wsum += wagg[v] * relu( b1 + dv^2*embW1[x[v]] + sum_e d_r*dv*embW1[x_r] )
__global__ void k_fconv(const int* __restrict__ needlist, const int* __restrict__ nneed_p,
                        const float* __restrict__ wagg, const int* __restrict__ x,
                        const int2* __restrict__ srowp,
                        const int* __restrict__ offs, const int* __restrict__ cnt,
                        const float* __restrict__ embW1, const float* __restrict__ b1,
                        float* __restrict__ wsum) {
    int lane = threadIdx.x & 63;
    int wib  = threadIdx.x >> 6;
    int wid  = blockIdx.x * (blockDim.x >> 6) + wib;
    int nw   = gridDim.x * (blockDim.x >> 6);
    int nn   = *nneed_p;
    const float4* __restrict__ ew = (const float4*)embW1;   // row r = ew + r*64
    float4 bfrag = ((const float4*)b1)[lane];
    float4 acc2 = {0.0f, 0.0f, 0.0f, 0.0f};

    for (int i = wid; i < nn; i += nw) {
        int v = needlist[i];
        int cv = cnt[v];
        float dv = rsqrtf((float)cv + 1.0f);
        float wa = wagg[v];
        float4 s = ew[(size_t)x[v] * 64 + lane];
        float w0 = dv * dv;
        float4 acc;
        acc.x = bfrag.x + w0 * s.x;
        acc.y = bfrag.y + w0 * s.y;
        acc.z = bfrag.z + w0 * s.z;
        acc.w = bfrag.w + w0 * s.w;
        int start = offs[v], m = cv;
        for (int base = 0; base < m; base += 64) {
            int mm = min(64, m - base);
            int xr = 0; float wr = 0.0f;
            if (lane < mm) {
                int2 pk = srowp[start + base + lane];      // one 8B load
                xr = pk.x;
                wr = __int_as_float(pk.y) * dv;
            }
            int e = 0;
            for (; e + 4 <= mm; e += 4) {
                int i0 = __shfl(xr, e),     i1 = __shfl(xr, e + 1);
                int i2 = __shfl(xr, e + 2), i3 = __shfl(xr, e + 3);
                float q0 = __shfl(wr, e),     q1 = __shfl(wr, e + 1);
                float q2 = __shfl(wr, e + 2), q3 = __shfl(wr, e + 3);
                float4 t0 = ew[(size_t)i0 * 64 + lane];
                float4 t1 = ew[(size_t)i1 * 64 + lane];
                float4 t2 = ew[(size_t)i2 * 64 + lane];
                float4 t3 = ew[(size_t)i3 * 64 + lane];
                acc.x += q0 * t0.x + q1 * t1.x + q2 * t2.x + q3 * t3.x;
                acc.y += q0 * t0.y + q1 * t1.y + q2 * t2.y + q3 * t3.y;
                acc.z += q0 * t0.z + q1 * t1.z + q2 * t2.z + q3 * t3.z;
                acc.w += q0 * t0.w + q1 * t1.w + q2 * t2.w + q3 * t3.w;
            }
            for (; e < mm; e++) {
                int i0 = __shfl(xr, e);
                float q0 = __shfl(wr, e);
                float4 t0 = ew[(size_t)i0 * 64 + lane];
                acc.x += q0 * t0.x;
                acc.y += q0 * t0.y;
                acc.z += q0 * t0.z;
                acc.w += q0 * t0.w;
            }
        }
        acc2.x += wa * fmaxf(acc.x, 0.0f);
        acc2.y += wa * fmaxf(acc.y, 0.0f);
        acc2.z += wa * fmaxf(acc.z, 0.0f);
        acc2.w += wa * fmaxf(acc.w, 0.0f);
    }

    __shared__ float red[4][H1D];
    red[wib][4 * lane + 0] = acc2.x;
    red[wib][4 * lane + 1] = acc2.y;
    red[wib][4 * lane + 2] = acc2.z;
    red[wib][4 * lane + 3] = acc2.w;
    __syncthreads();
    int t = threadIdx.x;
    float ssum = red[0][t] + red[1][t] + red[2][t] + red[3][t];
    atomicAdd(&wsum[(blockIdx.x & (NSL - 1)) * H1D + t], ssum);
}

// ---------- fused head (proven): reduce slices; zmean = (wsum@W2)/NP + b2; out = zmean@Wc + bc
__global__ void k_zout(const float* __restrict__ wsum, const float* __restrict__ W2,
                       const float* __restrict__ b2, const float* __restrict__ Wc,
                       const float* __restrict__ bc, float* __restrict__ out,
                       float inv_np) {
    __shared__ float ws[H1D];
    __shared__ float z[H2D];
    int t = threadIdx.x;
    float s = 0.0f;
#pragma unroll
    for (int c = 0; c < NSL; c++) s += wsum[c * H1D + t];
    ws[t] = s;
    __syncthreads();
    if (t < H2D) {
        float acc = 0.0f;
#pragma unroll 8
        for (int k = 0; k < H1D; k++) acc += ws[k] * W2[k * H2D + t];
        z[t] = b2[t] + acc * inv_np;
    }
    __syncthreads();
    int c = blockIdx.x * blockDim.x + t;
    float acc = bc[c];
#pragma unroll 8
    for (int j = 0; j < H2D; j++) acc += z[j] * Wc[(size_t)j * VOC + c];
    out[c] = acc;
}

extern "C" void kernel_launch(void* const* d_in, const int* in_sizes, int n_in,
                              void* d_out, int out_size, void* d_ws, size_t ws_size,
                              hipStream_t stream) {
    const int n  = in_sizes[0];
    const int ne = in_sizes[1] / 2;
    const int np = in_sizes[2];

    const int*   x    = (const int*)d_in[0];
    const int*   ei   = (const int*)d_in[1];
    const int*   xpos = (const int*)d_in[2];
    const float* emb  = (const float*)d_in[3];
    const float* W1   = (const float*)d_in[4];
    const float* b1   = (const float*)d_in[5];
    const float* W2   = (const float*)d_in[6];
    const float* b2   = (const float*)d_in[7];
    const float* Wc   = (const float*)d_in[8];
    const float* bc   = (const float*)d_in[9];
    float*       out  = (float*)d_out;

    const int* row = ei;       // edge_index[0]
    const int* col = ei + ne;  // edge_index[1]

    char* p = (char*)d_ws;
    auto alloc = [&](size_t bytes) {
        char* r = p;
        p += (bytes + 255) & ~(size_t)255;
        return r;
    };
    const int nb     = (n + 255) / 256;
    const int neb    = (ne + 255) / 256;
    const int nwords = nb * 8;   // (nb*256)/32 — padded so ballot stores stay in-bounds

    int*          cnt      = (int*)alloc((size_t)n * 4);
    int*          offs     = (int*)alloc((size_t)n * 4);
    int*          cursor   = (int*)alloc((size_t)n * 4);
    int*          count    = (int*)alloc((size_t)n * 4);
    int*          needlist = (int*)alloc((size_t)n * 4);
    unsigned int* needw    = (unsigned int*)alloc((size_t)nwords * 4);
    unsigned int* flagbits = (unsigned int*)alloc((size_t)nwords * 4);
    int2*         srowp    = (int2*)alloc((size_t)ne * 8);
    int*          nflag    = (int*)alloc(256 * 4);
    int*          total    = (int*)alloc(256 * 4);
    float*        wagg     = (float*)alloc((size_t)n * 4);
    float*        embW1    = (float*)alloc((size_t)VOC * H1D * 4);
    float*        wsum     = (float*)alloc((size_t)NSL * H1D * 4);

    k_init<<<nb, 256, 0, stream>>>(cnt, count, flagbits, needw, wagg, wsum,
                                   nflag, total, n, nwords);
    k_embW1C<<<VOC / RPB + 1, 256, 0, stream>>>(emb, W1, embW1, xpos, count, flagbits, np);
    k_hist<<<neb, 256, 0, stream>>>(row, col, flagbits, cnt, needw, ne);
    k_alloc<<<nb, 256, 0, stream>>>(needw, flagbits, cnt, count, wagg,
                                    needlist, nflag, total, offs, cursor, n);
    k_scatter<<<neb, 256, 0, stream>>>(row, col, needw, flagbits, count, x, cnt,
                                       cursor, srowp, wagg, ne);
    k_fconv<<<2048, 256, 0, stream>>>(needlist, nflag, wagg, x, srowp, offs, cnt,
                                      embW1, b1, wsum);
    k_zout<<<VOC / 256, 256, 0, stream>>>(wsum, W2, b2, Wc, bc, out, 1.0f / (float)np);
}